// Round 1
// baseline (471.721 us; speedup 1.0000x reference)
//
#include <hip/hip_runtime.h>

#define KCODES 1024
#define DDIM 128
#define HW 64
#define NPIX (32 * HW * HW)         // 131072 pixels
#define PLANE (HW * HW)             // 4096
#define BSTRIDE (DDIM * PLANE)      // 524288 floats per batch image
#define MARGIN 6e-5f
#define CAP_A 65536
#define CAP_B 8192
// margin budget: numpy fp32 band <=3.2e-5 (two ulp(128)/2 roundings per code
// pair) + phase1 split-bf16 err <=5e-6 + resolve fp32 err <=2e-6 -> 6e-5 safe.

typedef __attribute__((ext_vector_type(8))) short bf16x8;   // MFMA A/B frag
typedef __attribute__((ext_vector_type(4))) float f32x4;    // 16B vector
typedef __attribute__((ext_vector_type(16))) float f32x16;  // 32x32 C/D frag

__device__ inline unsigned short f2bf(float f) {            // RNE fp32->bf16
    unsigned u = __builtin_bit_cast(unsigned, f);
    unsigned r = u + 0x7FFFu + ((u >> 16) & 1u);
    return (unsigned short)(r >> 16);
}
__device__ inline float bf2f(unsigned short h) {
    unsigned u = ((unsigned)h) << 16;
    return __builtin_bit_cast(float, u);
}

// ---------------------------------------------------------------------------
// prep1: Bsum[k] = numpy-pairwise sum of codebook[k,:]^2 (fp32, contract off)
// ---------------------------------------------------------------------------
__global__ __launch_bounds__(256) void prep1_kernel(const float* __restrict__ cb,
                                                    float* __restrict__ Bsum) {
#pragma clang fp contract(off)
    int k = blockIdx.x * blockDim.x + threadIdx.x;
    if (k >= KCODES) return;
    const float* row = cb + k * DDIM;
    float r0,r1,r2,r3,r4,r5,r6,r7;
    r0 = row[0]*row[0]; r1 = row[1]*row[1]; r2 = row[2]*row[2]; r3 = row[3]*row[3];
    r4 = row[4]*row[4]; r5 = row[5]*row[5]; r6 = row[6]*row[6]; r7 = row[7]*row[7];
#pragma unroll
    for (int i = 8; i < DDIM; i += 8) {
        r0 += row[i+0]*row[i+0]; r1 += row[i+1]*row[i+1];
        r2 += row[i+2]*row[i+2]; r3 += row[i+3]*row[i+3];
        r4 += row[i+4]*row[i+4]; r5 += row[i+5]*row[i+5];
        r6 += row[i+6]*row[i+6]; r7 += row[i+7]*row[i+7];
    }
    Bsum[k] = ((r0+r1)+(r2+r3)) + ((r4+r5)+(r6+r7));
}

// ---------------------------------------------------------------------------
// prep2: split codebook into bf16 hi/lo, stored in 32x32x16 MFMA B-fragment
// order. ushort offset = ((c*8+s)*2+t)*512 + l*8 + j   (c=tile of 32 codes,
// s=kchunk of 16, t=hi/lo; lane l holds B[k=s*16+(l>>5)*8+j][n=c*32+(l&31)]).
// Each fragment is then a single coalesced dwordx4 per lane in phase1.
// ---------------------------------------------------------------------------
__global__ __launch_bounds__(256) void prep2_kernel(const float* __restrict__ cb,
                                                    unsigned short* __restrict__ bs) {
    int t = blockIdx.x * 256 + threadIdx.x;   // 16384 threads = 32c * 8s * 64l
    int c = t >> 9, s = (t >> 6) & 7, l = t & 63;
    int n = l & 31, half = l >> 5;
    int code = c * 32 + n;
    int d0 = s * 16 + half * 8;
    const float* row = cb + code * DDIM + d0;
    f32x4 f0 = *(const f32x4*)(row);
    f32x4 f1 = *(const f32x4*)(row + 4);
    int fh = ((c * 8 + s) * 2 + 0) * 512 + l * 8;
    int fl = fh + 512;
#pragma unroll
    for (int e = 0; e < 4; ++e) {
        float a = f0[e];
        unsigned short hb = f2bf(a);
        bs[fh + e] = hb;
        bs[fl + e] = f2bf(a - bf2f(hb));
        float b = f1[e];
        unsigned short hb2 = f2bf(b);
        bs[fh + 4 + e] = hb2;
        bs[fl + 4 + e] = f2bf(b - bf2f(hb2));
    }
}

// ---------------------------------------------------------------------------
// phase1: 32x32x16 MFMA distance + top-3 argmin. Block = 4 waves = 128 px
// (each wave independently owns 32 contiguous w of one h row x all 1024
// codes). No LDS staging: B fragments stream directly from the L2-resident
// 512KB split codebook as coalesced dwordx4; A (-2z hi/lo) lives in VGPRs.
// acc init = Bsum[k] -> MFMA output IS the distance (|z|^2 dropped: argmin-
// invariant). No barriers in the K/code loop.
// C/D layout: col(code)=lane&31, row(pixel)=(r&3)+8*(r>>2)+4*(lane>>5).
// ---------------------------------------------------------------------------
__global__ __launch_bounds__(256, 2) void phase1_mfma(
    const float* __restrict__ z, const float* __restrict__ cb,
    const unsigned short* __restrict__ bs, const float* __restrict__ Bsum,
    float* __restrict__ out, int* __restrict__ cntA, int2* __restrict__ listA,
    int* __restrict__ cntB, int* __restrict__ listB)
{
    __shared__ int idxb[128];
    const int tid = threadIdx.x;
    const int lane = tid & 63, wv = tid >> 6;
    const int wg = blockIdx.x;                 // 1024 blocks
    const int b = wg >> 5;
    const int h = (wg & 31) * 2 + (wv >> 1);
    const int w0 = (wv & 1) * 32;
    const int col = lane & 31, half = lane >> 5;

    // A fragments: pixel m=col -> w=w0+col; chunk s covers d = s*16+half*8+e
    const float* zbase = z + (size_t)b * BSTRIDE + h * HW + w0 + col;
    bf16x8 zhi[8], zlo[8];
#pragma unroll
    for (int s = 0; s < 8; ++s) {
        const float* zp = zbase + (size_t)(s * 16 + half * 8) * PLANE;
        bf16x8 hi, lo;
#pragma unroll
        for (int e = 0; e < 8; ++e) {
            float a = -2.0f * zp[(size_t)e * PLANE];
            unsigned short hb = f2bf(a);
            hi[e] = (short)hb; lo[e] = (short)f2bf(a - bf2f(hb));
        }
        zhi[s] = hi; zlo[s] = lo;
    }

    float m1[16], m2[16], m3[16]; int i1[16], i2[16];
#pragma unroll
    for (int r = 0; r < 16; ++r) {
        m1[r] = 3.4e38f; m2[r] = 3.4e38f; m3[r] = 3.4e38f; i1[r] = 0; i2[r] = 0;
    }

    const bf16x8* bfrag = (const bf16x8*)bs;
    for (int c = 0; c < 32; ++c) {
        int kcol = c * 32 + col;
        float bsv = Bsum[kcol];
        f32x16 acc;
#pragma unroll
        for (int r = 0; r < 16; ++r) acc[r] = bsv;
#pragma unroll
        for (int s = 0; s < 8; ++s) {
            bf16x8 bh = bfrag[((c * 8 + s) * 2 + 0) * 64 + lane];
            bf16x8 bl = bfrag[((c * 8 + s) * 2 + 1) * 64 + lane];
            acc = __builtin_amdgcn_mfma_f32_32x32x16_bf16(zhi[s], bh, acc, 0, 0, 0);
            acc = __builtin_amdgcn_mfma_f32_32x32x16_bf16(zlo[s], bh, acc, 0, 0, 0);
            acc = __builtin_amdgcn_mfma_f32_32x32x16_bf16(zhi[s], bl, acc, 0, 0, 0);
        }
#pragma unroll
        for (int r = 0; r < 16; ++r) {
            float dv = acc[r];
            bool lt1 = dv < m1[r];
            bool lt2 = dv < m2[r];
            m3[r] = lt2 ? m2[r] : fminf(m3[r], dv);
            m2[r] = lt1 ? m1[r] : (lt2 ? dv : m2[r]);
            i2[r] = lt1 ? i1[r] : (lt2 ? kcol : i2[r]);
            m1[r] = lt1 ? dv : m1[r];
            i1[r] = lt1 ? kcol : i1[r];
        }
    }

    // merge sorted-3 tuples across the 32 lanes (columns) sharing each row set
#pragma unroll
    for (int mask = 1; mask <= 16; mask <<= 1) {
#pragma unroll
        for (int r = 0; r < 16; ++r) {
            float b1 = __shfl_xor(m1[r], mask, 64);
            float b2 = __shfl_xor(m2[r], mask, 64);
            float b3 = __shfl_xor(m3[r], mask, 64);
            int  ib1 = __shfl_xor(i1[r], mask, 64);
            int  ib2 = __shfl_xor(i2[r], mask, 64);
            float a1 = m1[r], a2 = m2[r], a3 = m3[r];
            int  ia1 = i1[r], ia2 = i2[r];
            bool bf = (b1 < a1) || (b1 == a1 && ib1 < ia1);
            float x1 = bf ? b1 : a1;  int xi1 = bf ? ib1 : ia1;
            float x2 = bf ? b2 : a2;  int xi2 = bf ? ib2 : ia2;
            float x3 = bf ? b3 : a3;
            float y1 = bf ? a1 : b1;  int yi1 = bf ? ia1 : ib1;
            float y2 = bf ? a2 : b2;
            bool ys = (y1 < x2) || (y1 == x2 && yi1 < xi2);
            m1[r] = x1; i1[r] = xi1;
            m2[r] = ys ? y1 : x2;  i2[r] = ys ? yi1 : xi2;
            m3[r] = ys ? fminf(x2, y2) : fminf(x3, y1);
        }
    }

    if (col == 0) {                  // 2 writer lanes per wave (half=0/1)
#pragma unroll
        for (int r = 0; r < 16; ++r) {
            int row = (r & 3) + 8 * (r >> 2) + 4 * half;
            idxb[wv * 32 + row] = i1[r];
        }
    }
    __syncthreads();

    if (col == 0) {                  // ambiguity records (rare)
#pragma unroll
        for (int r = 0; r < 16; ++r) {
            if (m2[r] - m1[r] <= MARGIN) {
                int row = (r & 3) + 8 * (r >> 2) + 4 * half;
                int pix = (b * 64 + h) * 64 + w0 + row;
                int pos = atomicAdd(cntA, 1);
                if (pos < CAP_A) {
                    int2 rec; rec.x = pix; rec.y = i1[r] | (i2[r] << 16);
                    listA[pos] = rec;
                }
                if (m3[r] - m1[r] <= MARGIN) {
                    int pb = atomicAdd(cntB, 1);
                    if (pb < CAP_B) listB[pb] = pix;
                }
            }
        }
    }

    // write guess: lane -> pixel w = w0+col; half selects d in [half*64, +64)
    int widx = idxb[wv * 32 + col];
    const float* crow = cb + widx * DDIM + half * 64;
    float* ob = out + (size_t)b * BSTRIDE + (size_t)(half * 64) * PLANE
              + h * HW + w0 + col;
#pragma unroll
    for (int dd = 0; dd < 16; ++dd) {
        f32x4 c4 = *(const f32x4*)(crow + dd * 4);
        ob[(size_t)(dd * 4 + 0) * PLANE] = c4[0];
        ob[(size_t)(dd * 4 + 1) * PLANE] = c4[1];
        ob[(size_t)(dd * 4 + 2) * PLANE] = c4[2];
        ob[(size_t)(dd * 4 + 3) * PLANE] = c4[3];
    }
}

// ---------------------------------------------------------------------------
// phase3a: resolve 2-candidate ambiguous pixels. One wave per item.
// z row fetched with one parallel 64-lane round trip into LDS; numpy-exact:
//   A    = numpy-pairwise sum of z^2 (fp32, contract off)
//   p    = dot in fp64 (lane-split + shuffle reduce; order-agnostic, err~1e-13)
//   D_k  = fl32( fl32(A + Bsum_k) - fl32(2*p) );  winner = lex min (D, k)
// No __syncthreads in the item loop (waves diverge); within-wave LDS ops are
// in-order on CDNA so write->read needs no barrier.
// ---------------------------------------------------------------------------
__global__ __launch_bounds__(256, 4) void phase3a_kernel(
    const float* __restrict__ z, const float* __restrict__ cb,
    const float* __restrict__ Bsum, float* __restrict__ out,
    const int* __restrict__ cntA, const int2* __restrict__ listA)
{
    __shared__ float zsh[4][128];
    const int tid = threadIdx.x, lane = tid & 63, wv = tid >> 6;
    int gwave = (blockIdx.x * 256 + tid) >> 6;
    int nwaves = gridDim.x * 4;
    int nitems = *cntA; if (nitems > CAP_A) nitems = CAP_A;

    for (int item = gwave; item < nitems; item += nwaves) {
        int2 rec = listA[item];
        int pix = rec.x;
        int k1 = rec.y & 0xFFFF, k2 = rec.y >> 16;
        int b = pix >> 12, h = (pix >> 6) & 63, w = pix & 63;
        const float* zp = z + (size_t)b * BSTRIDE + h * HW + w;

        float za = zp[(size_t)lane * PLANE];
        float zb = zp[(size_t)(lane + 64) * PLANE];
        zsh[wv][lane] = za;
        zsh[wv][lane + 64] = zb;

        // numpy pairwise A from LDS (broadcast reads; all lanes redundant)
        float Apair;
        {
#pragma clang fp contract(off)
            const float* zr = zsh[wv];
            float r0,r1,r2,r3,r4,r5,r6,r7;
            r0 = zr[0]*zr[0]; r1 = zr[1]*zr[1]; r2 = zr[2]*zr[2]; r3 = zr[3]*zr[3];
            r4 = zr[4]*zr[4]; r5 = zr[5]*zr[5]; r6 = zr[6]*zr[6]; r7 = zr[7]*zr[7];
#pragma unroll
            for (int i = 8; i < DDIM; i += 8) {
                r0 += zr[i+0]*zr[i+0]; r1 += zr[i+1]*zr[i+1];
                r2 += zr[i+2]*zr[i+2]; r3 += zr[i+3]*zr[i+3];
                r4 += zr[i+4]*zr[i+4]; r5 += zr[i+5]*zr[i+5];
                r6 += zr[i+6]*zr[i+6]; r7 += zr[i+7]*zr[i+7];
            }
            Apair = ((r0+r1)+(r2+r3)) + ((r4+r5)+(r6+r7));
        }

        // fp64 dots for k1,k2 (coalesced codebook reads)
        const float* c1 = cb + (size_t)k1 * DDIM;
        const float* c2 = cb + (size_t)k2 * DDIM;
        double p1 = fma((double)za, (double)c1[lane],
                        (double)zb * (double)c1[lane + 64]);
        double p2 = fma((double)za, (double)c2[lane],
                        (double)zb * (double)c2[lane + 64]);
        for (int off = 32; off; off >>= 1) {
            p1 += __shfl_xor(p1, off, 64);
            p2 += __shfl_xor(p2, off, 64);
        }
        float u1 = (float)(2.0 * p1), u2 = (float)(2.0 * p2);
        float D1, D2;
        {
#pragma clang fp contract(off)
            float t1 = Apair + Bsum[k1];
            float t2 = Apair + Bsum[k2];
            D1 = t1 - u1; D2 = t2 - u2;
        }
        int wk = (D1 < D2 || (D1 == D2 && k1 < k2)) ? k1 : k2;

        const float* cw = cb + (size_t)wk * DDIM;
        float* op = out + (size_t)b * BSTRIDE + h * HW + w;
        op[(size_t)lane * PLANE] = cw[lane];
        op[(size_t)(lane + 64) * PLANE] = cw[lane + 64];
    }
}

// ---------------------------------------------------------------------------
// phase3b: full-scan numpy-exact resolve for >=3-candidate pixels (rare,
// expected O(10)). One block per item; lane owns 4 codes. Runs AFTER
// phase3a so its writes win.
// ---------------------------------------------------------------------------
__global__ __launch_bounds__(256, 2) void phase3b_kernel(
    const float* __restrict__ z, const float* __restrict__ cb,
    const float* __restrict__ Bsum, float* __restrict__ out,
    const int* __restrict__ cntB, const int* __restrict__ listB)
{
    __shared__ float zr[128];
    __shared__ float sD[256];
    __shared__ int   sK[256];
    const int tid = threadIdx.x;
    int nitems = *cntB; if (nitems > CAP_B) nitems = CAP_B;

    for (int item = blockIdx.x; item < nitems; item += gridDim.x) {
        int pix = listB[item];
        int b = pix >> 12, h = (pix >> 6) & 63, w = pix & 63;
        const float* zp = z + (size_t)b * BSTRIDE + h * HW + w;
        __syncthreads();                       // zr reuse guard
        if (tid < 128) zr[tid] = zp[(size_t)tid * PLANE];
        __syncthreads();

        // fp32 distances for this thread's 4 codes
        float s0v, s1v, s2v, s3v;
#define SDOT(OUT, J) { int k = tid * 4 + (J); const float* c = cb + (size_t)k * DDIM; \
        float a0=0.f,a1=0.f,a2=0.f,a3=0.f; \
        for (int i = 0; i < DDIM; i += 4) { \
            a0 = __builtin_fmaf(zr[i+0], c[i+0], a0); \
            a1 = __builtin_fmaf(zr[i+1], c[i+1], a1); \
            a2 = __builtin_fmaf(zr[i+2], c[i+2], a2); \
            a3 = __builtin_fmaf(zr[i+3], c[i+3], a3); } \
        OUT = Bsum[k] - 2.0f * ((a0+a1)+(a2+a3)); }
        SDOT(s0v, 0) SDOT(s1v, 1) SDOT(s2v, 2) SDOT(s3v, 3)
#undef SDOT
        float lmin = fminf(fminf(s0v, s1v), fminf(s2v, s3v));
        sD[tid] = lmin; __syncthreads();
        for (int st = 128; st; st >>= 1) {
            if (tid < st) sD[tid] = fminf(sD[tid], sD[tid + st]);
            __syncthreads();
        }
        float smin = sD[0];
        __syncthreads();

        // numpy pairwise A (redundant per thread)
        float Apair;
        {
#pragma clang fp contract(off)
            float r0,r1,r2,r3,r4,r5,r6,r7;
            r0 = zr[0]*zr[0]; r1 = zr[1]*zr[1]; r2 = zr[2]*zr[2]; r3 = zr[3]*zr[3];
            r4 = zr[4]*zr[4]; r5 = zr[5]*zr[5]; r6 = zr[6]*zr[6]; r7 = zr[7]*zr[7];
#pragma unroll
            for (int i = 8; i < DDIM; i += 8) {
                r0 += zr[i+0]*zr[i+0]; r1 += zr[i+1]*zr[i+1];
                r2 += zr[i+2]*zr[i+2]; r3 += zr[i+3]*zr[i+3];
                r4 += zr[i+4]*zr[i+4]; r5 += zr[i+5]*zr[i+5];
                r6 += zr[i+6]*zr[i+6]; r7 += zr[i+7]*zr[i+7];
            }
            Apair = ((r0+r1)+(r2+r3)) + ((r4+r5)+(r6+r7));
        }

        float bd = 3.4e38f; int bk = 1 << 30;
#define CAND(SV, J) { if (SV <= smin + MARGIN) { \
        int k = tid * 4 + (J); const float* c = cb + (size_t)k * DDIM; \
        double dacc = 0.0; \
        for (int i = 0; i < DDIM; ++i) dacc = fma((double)zr[i], (double)c[i], dacc); \
        float u = (float)(2.0 * dacc); \
        float tt, Dk; \
        { float tA = Apair + Bsum[k]; tt = tA; } \
        Dk = tt - u; \
        if (Dk < bd || (Dk == bd && k < bk)) { bd = Dk; bk = k; } } }
        CAND(s0v, 0) CAND(s1v, 1) CAND(s2v, 2) CAND(s3v, 3)
#undef CAND
        sD[tid] = bd; sK[tid] = bk; __syncthreads();
        for (int st = 128; st; st >>= 1) {
            if (tid < st) {
                float od = sD[tid + st]; int ok = sK[tid + st];
                if (od < sD[tid] || (od == sD[tid] && ok < sK[tid])) {
                    sD[tid] = od; sK[tid] = ok;
                }
            }
            __syncthreads();
        }
        int wk = sK[0];
        if (tid < 128)
            out[(size_t)b * BSTRIDE + (size_t)tid * PLANE + h * HW + w] =
                cb[(size_t)wk * DDIM + tid];
    }
}

// ---------------------------------------------------------------------------
extern "C" void kernel_launch(void* const* d_in, const int* in_sizes, int n_in,
                              void* d_out, int out_size, void* d_ws, size_t ws_size,
                              hipStream_t stream) {
    const float* z  = (const float*)d_in[0];
    const float* cb = (const float*)d_in[1];
    float* out = (float*)d_out;

    // ws: Bsum 4K | cnts 4K | bsplit 512K | listA 512K (int2) | listB 32K
    float* Bsum = (float*)d_ws;
    int* cntA = (int*)((char*)d_ws + 4096);
    int* cntB = cntA + 1;
    unsigned short* bsplit = (unsigned short*)((char*)d_ws + 8192);
    int2* listA = (int2*)((char*)d_ws + 8192 + 524288);
    int* listB  = (int*)((char*)d_ws + 8192 + 524288 + 524288);

    hipMemsetAsync(cntA, 0, 2 * sizeof(int), stream);
    prep1_kernel<<<KCODES / 256, 256, 0, stream>>>(cb, Bsum);
    prep2_kernel<<<64, 256, 0, stream>>>(cb, bsplit);
    phase1_mfma<<<NPIX / 128, 256, 0, stream>>>(z, cb, bsplit, Bsum, out,
                                                cntA, listA, cntB, listB);
    phase3a_kernel<<<2048, 256, 0, stream>>>(z, cb, Bsum, out, cntA, listA);
    phase3b_kernel<<<256, 256, 0, stream>>>(z, cb, Bsum, out, cntB, listB);
}

// Round 2
// 405.777 us; speedup vs baseline: 1.1625x; 1.1625x over previous
//
#include <hip/hip_runtime.h>

#define KCODES 1024
#define DDIM 128
#define HW 64
#define NPIX (32 * HW * HW)         // 131072 pixels
#define PLANE (HW * HW)             // 4096
#define BSTRIDE (DDIM * PLANE)      // 524288 floats per batch image
#define MARGIN 6e-5f
#define CAP_A 65536
#define CAP_B 8192
// margin budget: numpy fp32 band <=3.2e-5 (two ulp(128)/2 roundings per code
// pair) + phase1 split-bf16 err <=5e-6 + resolve fp32 err <=2e-6 -> 6e-5 safe.

typedef __attribute__((ext_vector_type(8))) short bf16x8;   // MFMA A/B frag
typedef __attribute__((ext_vector_type(4))) float f32x4;    // 16B vector
typedef __attribute__((ext_vector_type(16))) float f32x16;  // 32x32 C/D frag

__device__ inline unsigned short f2bf(float f) {            // RNE fp32->bf16
    unsigned u = __builtin_bit_cast(unsigned, f);
    unsigned r = u + 0x7FFFu + ((u >> 16) & 1u);
    return (unsigned short)(r >> 16);
}
__device__ inline float bf2f(unsigned short h) {
    unsigned u = ((unsigned)h) << 16;
    return __builtin_bit_cast(float, u);
}

// async global->LDS, 16B per lane (wave-uniform LDS base + lane*16)
__device__ inline void gll16(const void* g, void* l) {
    __builtin_amdgcn_global_load_lds(
        (const __attribute__((address_space(1))) unsigned int*)g,
        (__attribute__((address_space(3))) unsigned int*)l, 16, 0, 0);
}

// ---------------------------------------------------------------------------
// prep (merged): blocks 0..3  -> Bsum[k] = numpy-pairwise sum of cb[k,:]^2
//               blocks 4..67 -> split codebook bf16 hi/lo in 32x32x16 MFMA
// B-fragment order: ushort off = ((c*8+s)*2+t)*512 + l*8 + j  (c=tile of 32
// codes, s=kchunk of 16, t=hi/lo; lane l holds B[k=s*16+(l>>5)*8+j][n=c*32+(l&31)])
// ---------------------------------------------------------------------------
__global__ __launch_bounds__(256) void prep_kernel(const float* __restrict__ cb,
                                                   float* __restrict__ Bsum,
                                                   unsigned short* __restrict__ bs) {
    int bid = blockIdx.x;
    if (bid < 4) {
#pragma clang fp contract(off)
        int k = bid * 256 + threadIdx.x;
        const float* row = cb + k * DDIM;
        float r0,r1,r2,r3,r4,r5,r6,r7;
        r0 = row[0]*row[0]; r1 = row[1]*row[1]; r2 = row[2]*row[2]; r3 = row[3]*row[3];
        r4 = row[4]*row[4]; r5 = row[5]*row[5]; r6 = row[6]*row[6]; r7 = row[7]*row[7];
#pragma unroll
        for (int i = 8; i < DDIM; i += 8) {
            r0 += row[i+0]*row[i+0]; r1 += row[i+1]*row[i+1];
            r2 += row[i+2]*row[i+2]; r3 += row[i+3]*row[i+3];
            r4 += row[i+4]*row[i+4]; r5 += row[i+5]*row[i+5];
            r6 += row[i+6]*row[i+6]; r7 += row[i+7]*row[i+7];
        }
        Bsum[k] = ((r0+r1)+(r2+r3)) + ((r4+r5)+(r6+r7));
    } else {
        int t = (bid - 4) * 256 + threadIdx.x;   // 16384 threads = 32c*8s*64l
        int c = t >> 9, s = (t >> 6) & 7, l = t & 63;
        int n = l & 31, half = l >> 5;
        int code = c * 32 + n;
        int d0 = s * 16 + half * 8;
        const float* row = cb + code * DDIM + d0;
        f32x4 f0 = *(const f32x4*)(row);
        f32x4 f1 = *(const f32x4*)(row + 4);
        int fh = ((c * 8 + s) * 2 + 0) * 512 + l * 8;
        int fl = fh + 512;
#pragma unroll
        for (int e = 0; e < 4; ++e) {
            float a = f0[e];
            unsigned short hb = f2bf(a);
            bs[fh + e] = hb;
            bs[fl + e] = f2bf(a - bf2f(hb));
            float b = f1[e];
            unsigned short hb2 = f2bf(b);
            bs[fh + 4 + e] = hb2;
            bs[fl + 4 + e] = f2bf(b - bf2f(hb2));
        }
    }
}

// ---------------------------------------------------------------------------
// phase1: 32x32x16 MFMA distance + top-3 argmin.
// Block = 4 waves = 128 px; each wave owns 32 contiguous w of one h row.
// B tiles (16KB = 32 codes x 128d x hi/lo) are double-buffered in LDS,
// shared by all 4 waves, staged with global_load_lds dwordx4 (linear layout
// both sides; prep stored fragment order). One barrier per c-tile; prefetch
// of tile c+1 issued before compute on tile c, so the vmcnt drain at the
// barrier is covered by ~24 MFMAs + tracking VALU.
// acc init = Bsum[k] -> MFMA output IS the distance (|z|^2 dropped).
// C/D layout: col(code)=lane&31, row(pixel)=(r&3)+8*(r>>2)+4*(lane>>5).
// ---------------------------------------------------------------------------
__global__ __launch_bounds__(256, 2) void phase1_mfma(
    const float* __restrict__ z, const float* __restrict__ cb,
    const unsigned short* __restrict__ bs, const float* __restrict__ Bsum,
    float* __restrict__ out, int* __restrict__ cntA, int2* __restrict__ listA,
    int* __restrict__ cntB, int* __restrict__ listB)
{
    __shared__ __align__(16) unsigned short btile[2][8192];   // 2 x 16KB
    __shared__ int idxb[128];
    const int tid = threadIdx.x;
    const int lane = tid & 63, wv = tid >> 6;
    const int wg = blockIdx.x;                 // 1024 blocks
    const int b = wg >> 5;
    const int h = (wg & 31) * 2 + (wv >> 1);
    const int w0 = (wv & 1) * 32;
    const int col = lane & 31, half = lane >> 5;

    // A fragments: pixel m=col -> w=w0+col; chunk s covers d = s*16+half*8+e
    const float* zbase = z + (size_t)b * BSTRIDE + h * HW + w0 + col;
    bf16x8 zhi[8], zlo[8];
#pragma unroll
    for (int s = 0; s < 8; ++s) {
        const float* zp = zbase + (size_t)(s * 16 + half * 8) * PLANE;
        bf16x8 hi, lo;
#pragma unroll
        for (int e = 0; e < 8; ++e) {
            float a = -2.0f * zp[(size_t)e * PLANE];
            unsigned short hb = f2bf(a);
            hi[e] = (short)hb; lo[e] = (short)f2bf(a - bf2f(hb));
        }
        zhi[s] = hi; zlo[s] = lo;
    }

    float m1[16], m2[16], m3[16]; int i1[16], i2[16];
#pragma unroll
    for (int r = 0; r < 16; ++r) {
        m1[r] = 3.4e38f; m2[r] = 3.4e38f; m3[r] = 3.4e38f; i1[r] = 0; i2[r] = 0;
    }

    // staging: wave wv owns bytes [wv*4096, +4096) of each 16KB tile
    const char* bbase = (const char*)bs;
    char* lbase0 = (char*)&btile[0][0] + wv * 4096;
    char* lbase1 = (char*)&btile[1][0] + wv * 4096;

#define STAGE(BUF, C) do {                                                   \
        const char* _src = bbase + (C) * 16384 + wv * 4096 + lane * 16;      \
        char* _dst = (BUF) ? lbase1 : lbase0;                                \
        gll16(_src,        _dst);                                            \
        gll16(_src + 1024, _dst + 1024);                                     \
        gll16(_src + 2048, _dst + 2048);                                     \
        gll16(_src + 3072, _dst + 3072);                                     \
    } while (0)

    STAGE(0, 0);
    __syncthreads();

    for (int c = 0; c < 32; ++c) {
        const int cur = c & 1;
        if (c < 31) STAGE(cur ^ 1, c + 1);     // prefetch next tile

        const bf16x8* bf = (const bf16x8*)btile[cur];
        int kcol = c * 32 + col;
        float bsv = Bsum[kcol];
        f32x16 acc;
#pragma unroll
        for (int r = 0; r < 16; ++r) acc[r] = bsv;
#pragma unroll
        for (int s = 0; s < 8; ++s) {
            bf16x8 bh = bf[(s * 2 + 0) * 64 + lane];
            bf16x8 bl = bf[(s * 2 + 1) * 64 + lane];
            acc = __builtin_amdgcn_mfma_f32_32x32x16_bf16(zhi[s], bh, acc, 0, 0, 0);
            acc = __builtin_amdgcn_mfma_f32_32x32x16_bf16(zlo[s], bh, acc, 0, 0, 0);
            acc = __builtin_amdgcn_mfma_f32_32x32x16_bf16(zhi[s], bl, acc, 0, 0, 0);
        }
        // top-3 sorted insert: values via min/med3, indices via cndmask
#pragma unroll
        for (int r = 0; r < 16; ++r) {
            float dv = acc[r];
            bool lt1 = dv < m1[r];
            bool lt2 = dv < m2[r];
            i2[r] = lt1 ? i1[r] : (lt2 ? kcol : i2[r]);
            i1[r] = lt1 ? kcol : i1[r];
            m3[r] = __builtin_amdgcn_fmed3f(m2[r], m3[r], dv);
            m2[r] = __builtin_amdgcn_fmed3f(m1[r], m2[r], dv);
            m1[r] = fminf(m1[r], dv);
        }
        __syncthreads();                       // reads done + prefetch landed
    }
#undef STAGE

    // merge sorted-3 tuples across the 32 lanes (columns) sharing each row set
#pragma unroll
    for (int mask = 1; mask <= 16; mask <<= 1) {
#pragma unroll
        for (int r = 0; r < 16; ++r) {
            float b1 = __shfl_xor(m1[r], mask, 64);
            float b2 = __shfl_xor(m2[r], mask, 64);
            float b3 = __shfl_xor(m3[r], mask, 64);
            int  ib1 = __shfl_xor(i1[r], mask, 64);
            int  ib2 = __shfl_xor(i2[r], mask, 64);
            float a1 = m1[r], a2 = m2[r], a3 = m3[r];
            int  ia1 = i1[r], ia2 = i2[r];
            bool bf2 = (b1 < a1) || (b1 == a1 && ib1 < ia1);
            float x1 = bf2 ? b1 : a1;  int xi1 = bf2 ? ib1 : ia1;
            float x2 = bf2 ? b2 : a2;  int xi2 = bf2 ? ib2 : ia2;
            float x3 = bf2 ? b3 : a3;
            float y1 = bf2 ? a1 : b1;  int yi1 = bf2 ? ia1 : ib1;
            float y2 = bf2 ? a2 : b2;
            bool ys = (y1 < x2) || (y1 == x2 && yi1 < xi2);
            m1[r] = x1; i1[r] = xi1;
            m2[r] = ys ? y1 : x2;  i2[r] = ys ? yi1 : xi2;
            m3[r] = ys ? fminf(x2, y2) : fminf(x3, y1);
        }
    }

    if (col == 0) {                  // 2 writer lanes per wave (half=0/1)
#pragma unroll
        for (int r = 0; r < 16; ++r) {
            int row = (r & 3) + 8 * (r >> 2) + 4 * half;
            idxb[wv * 32 + row] = i1[r];
        }
    }
    __syncthreads();

    if (col == 0) {                  // ambiguity records (rare)
#pragma unroll
        for (int r = 0; r < 16; ++r) {
            if (m2[r] - m1[r] <= MARGIN) {
                int row = (r & 3) + 8 * (r >> 2) + 4 * half;
                int pix = (b * 64 + h) * 64 + w0 + row;
                int pos = atomicAdd(cntA, 1);
                if (pos < CAP_A) {
                    int2 rec; rec.x = pix; rec.y = i1[r] | (i2[r] << 16);
                    listA[pos] = rec;
                }
                if (m3[r] - m1[r] <= MARGIN) {
                    int pb = atomicAdd(cntB, 1);
                    if (pb < CAP_B) listB[pb] = pix;
                }
            }
        }
    }

    // write guess: lane -> pixel w = w0+col; half selects d in [half*64, +64)
    int widx = idxb[wv * 32 + col];
    const float* crow = cb + widx * DDIM + half * 64;
    float* ob = out + (size_t)b * BSTRIDE + (size_t)(half * 64) * PLANE
              + h * HW + w0 + col;
#pragma unroll
    for (int dd = 0; dd < 16; ++dd) {
        f32x4 c4 = *(const f32x4*)(crow + dd * 4);
        ob[(size_t)(dd * 4 + 0) * PLANE] = c4[0];
        ob[(size_t)(dd * 4 + 1) * PLANE] = c4[1];
        ob[(size_t)(dd * 4 + 2) * PLANE] = c4[2];
        ob[(size_t)(dd * 4 + 3) * PLANE] = c4[3];
    }
}

// ---------------------------------------------------------------------------
// phase3a: resolve 2-candidate ambiguous pixels. One wave per item.
//   A    = numpy-pairwise sum of z^2 (fp32, contract off)
//   p    = dot in fp64 (lane-split + shuffle reduce; order-agnostic)
//   D_k  = fl32( fl32(A + Bsum_k) - fl32(2*p) );  winner = lex min (D, k)
// ---------------------------------------------------------------------------
__global__ __launch_bounds__(256, 4) void phase3a_kernel(
    const float* __restrict__ z, const float* __restrict__ cb,
    const float* __restrict__ Bsum, float* __restrict__ out,
    const int* __restrict__ cntA, const int2* __restrict__ listA)
{
    __shared__ float zsh[4][128];
    const int tid = threadIdx.x, lane = tid & 63, wv = tid >> 6;
    int gwave = (blockIdx.x * 256 + tid) >> 6;
    int nwaves = gridDim.x * 4;
    int nitems = *cntA; if (nitems > CAP_A) nitems = CAP_A;

    for (int item = gwave; item < nitems; item += nwaves) {
        int2 rec = listA[item];
        int pix = rec.x;
        int k1 = rec.y & 0xFFFF, k2 = rec.y >> 16;
        int b = pix >> 12, h = (pix >> 6) & 63, w = pix & 63;
        const float* zp = z + (size_t)b * BSTRIDE + h * HW + w;

        float za = zp[(size_t)lane * PLANE];
        float zb = zp[(size_t)(lane + 64) * PLANE];
        zsh[wv][lane] = za;
        zsh[wv][lane + 64] = zb;

        float Apair;
        {
#pragma clang fp contract(off)
            const float* zr = zsh[wv];
            float r0,r1,r2,r3,r4,r5,r6,r7;
            r0 = zr[0]*zr[0]; r1 = zr[1]*zr[1]; r2 = zr[2]*zr[2]; r3 = zr[3]*zr[3];
            r4 = zr[4]*zr[4]; r5 = zr[5]*zr[5]; r6 = zr[6]*zr[6]; r7 = zr[7]*zr[7];
#pragma unroll
            for (int i = 8; i < DDIM; i += 8) {
                r0 += zr[i+0]*zr[i+0]; r1 += zr[i+1]*zr[i+1];
                r2 += zr[i+2]*zr[i+2]; r3 += zr[i+3]*zr[i+3];
                r4 += zr[i+4]*zr[i+4]; r5 += zr[i+5]*zr[i+5];
                r6 += zr[i+6]*zr[i+6]; r7 += zr[i+7]*zr[i+7];
            }
            Apair = ((r0+r1)+(r2+r3)) + ((r4+r5)+(r6+r7));
        }

        const float* c1 = cb + (size_t)k1 * DDIM;
        const float* c2 = cb + (size_t)k2 * DDIM;
        double p1 = fma((double)za, (double)c1[lane],
                        (double)zb * (double)c1[lane + 64]);
        double p2 = fma((double)za, (double)c2[lane],
                        (double)zb * (double)c2[lane + 64]);
        for (int off = 32; off; off >>= 1) {
            p1 += __shfl_xor(p1, off, 64);
            p2 += __shfl_xor(p2, off, 64);
        }
        float u1 = (float)(2.0 * p1), u2 = (float)(2.0 * p2);
        float D1, D2;
        {
#pragma clang fp contract(off)
            float t1 = Apair + Bsum[k1];
            float t2 = Apair + Bsum[k2];
            D1 = t1 - u1; D2 = t2 - u2;
        }
        int wk = (D1 < D2 || (D1 == D2 && k1 < k2)) ? k1 : k2;

        const float* cw = cb + (size_t)wk * DDIM;
        float* op = out + (size_t)b * BSTRIDE + h * HW + w;
        op[(size_t)lane * PLANE] = cw[lane];
        op[(size_t)(lane + 64) * PLANE] = cw[lane + 64];
    }
}

// ---------------------------------------------------------------------------
// phase3b: full-scan numpy-exact resolve for >=3-candidate pixels (rare).
// One block per item; lane owns 4 codes. Runs AFTER phase3a so writes win.
// ---------------------------------------------------------------------------
__global__ __launch_bounds__(256, 2) void phase3b_kernel(
    const float* __restrict__ z, const float* __restrict__ cb,
    const float* __restrict__ Bsum, float* __restrict__ out,
    const int* __restrict__ cntB, const int* __restrict__ listB)
{
    __shared__ float zr[128];
    __shared__ float sD[256];
    __shared__ int   sK[256];
    const int tid = threadIdx.x;
    int nitems = *cntB; if (nitems > CAP_B) nitems = CAP_B;

    for (int item = blockIdx.x; item < nitems; item += gridDim.x) {
        int pix = listB[item];
        int b = pix >> 12, h = (pix >> 6) & 63, w = pix & 63;
        const float* zp = z + (size_t)b * BSTRIDE + h * HW + w;
        __syncthreads();                       // zr reuse guard
        if (tid < 128) zr[tid] = zp[(size_t)tid * PLANE];
        __syncthreads();

        float s0v, s1v, s2v, s3v;
#define SDOT(OUT, J) { int k = tid * 4 + (J); const float* c = cb + (size_t)k * DDIM; \
        float a0=0.f,a1=0.f,a2=0.f,a3=0.f; \
        for (int i = 0; i < DDIM; i += 4) { \
            a0 = __builtin_fmaf(zr[i+0], c[i+0], a0); \
            a1 = __builtin_fmaf(zr[i+1], c[i+1], a1); \
            a2 = __builtin_fmaf(zr[i+2], c[i+2], a2); \
            a3 = __builtin_fmaf(zr[i+3], c[i+3], a3); } \
        OUT = Bsum[k] - 2.0f * ((a0+a1)+(a2+a3)); }
        SDOT(s0v, 0) SDOT(s1v, 1) SDOT(s2v, 2) SDOT(s3v, 3)
#undef SDOT
        float lmin = fminf(fminf(s0v, s1v), fminf(s2v, s3v));
        sD[tid] = lmin; __syncthreads();
        for (int st = 128; st; st >>= 1) {
            if (tid < st) sD[tid] = fminf(sD[tid], sD[tid + st]);
            __syncthreads();
        }
        float smin = sD[0];
        __syncthreads();

        float Apair;
        {
#pragma clang fp contract(off)
            float r0,r1,r2,r3,r4,r5,r6,r7;
            r0 = zr[0]*zr[0]; r1 = zr[1]*zr[1]; r2 = zr[2]*zr[2]; r3 = zr[3]*zr[3];
            r4 = zr[4]*zr[4]; r5 = zr[5]*zr[5]; r6 = zr[6]*zr[6]; r7 = zr[7]*zr[7];
#pragma unroll
            for (int i = 8; i < DDIM; i += 8) {
                r0 += zr[i+0]*zr[i+0]; r1 += zr[i+1]*zr[i+1];
                r2 += zr[i+2]*zr[i+2]; r3 += zr[i+3]*zr[i+3];
                r4 += zr[i+4]*zr[i+4]; r5 += zr[i+5]*zr[i+5];
                r6 += zr[i+6]*zr[i+6]; r7 += zr[i+7]*zr[i+7];
            }
            Apair = ((r0+r1)+(r2+r3)) + ((r4+r5)+(r6+r7));
        }

        float bd = 3.4e38f; int bk = 1 << 30;
#define CAND(SV, J) { if (SV <= smin + MARGIN) { \
        int k = tid * 4 + (J); const float* c = cb + (size_t)k * DDIM; \
        double dacc = 0.0; \
        for (int i = 0; i < DDIM; ++i) dacc = fma((double)zr[i], (double)c[i], dacc); \
        float u = (float)(2.0 * dacc); \
        float tt, Dk; \
        { float tA = Apair + Bsum[k]; tt = tA; } \
        Dk = tt - u; \
        if (Dk < bd || (Dk == bd && k < bk)) { bd = Dk; bk = k; } } }
        CAND(s0v, 0) CAND(s1v, 1) CAND(s2v, 2) CAND(s3v, 3)
#undef CAND
        sD[tid] = bd; sK[tid] = bk; __syncthreads();
        for (int st = 128; st; st >>= 1) {
            if (tid < st) {
                float od = sD[tid + st]; int ok = sK[tid + st];
                if (od < sD[tid] || (od == sD[tid] && ok < sK[tid])) {
                    sD[tid] = od; sK[tid] = ok;
                }
            }
            __syncthreads();
        }
        int wk = sK[0];
        if (tid < 128)
            out[(size_t)b * BSTRIDE + (size_t)tid * PLANE + h * HW + w] =
                cb[(size_t)wk * DDIM + tid];
    }
}

// ---------------------------------------------------------------------------
extern "C" void kernel_launch(void* const* d_in, const int* in_sizes, int n_in,
                              void* d_out, int out_size, void* d_ws, size_t ws_size,
                              hipStream_t stream) {
    const float* z  = (const float*)d_in[0];
    const float* cb = (const float*)d_in[1];
    float* out = (float*)d_out;

    // ws: Bsum 4K | cnts 4K | bsplit 512K | listA 512K (int2) | listB 32K
    float* Bsum = (float*)d_ws;
    int* cntA = (int*)((char*)d_ws + 4096);
    int* cntB = cntA + 1;
    unsigned short* bsplit = (unsigned short*)((char*)d_ws + 8192);
    int2* listA = (int2*)((char*)d_ws + 8192 + 524288);
    int* listB  = (int*)((char*)d_ws + 8192 + 524288 + 524288);

    hipMemsetAsync(cntA, 0, 2 * sizeof(int), stream);
    prep_kernel<<<68, 256, 0, stream>>>(cb, Bsum, bsplit);
    phase1_mfma<<<NPIX / 128, 256, 0, stream>>>(z, cb, bsplit, Bsum, out,
                                                cntA, listA, cntB, listB);
    phase3a_kernel<<<512, 256, 0, stream>>>(z, cb, Bsum, out, cntA, listA);
    phase3b_kernel<<<64, 256, 0, stream>>>(z, cb, Bsum, out, cntB, listB);
}